// Round 4
// baseline (7872.409 us; speedup 1.0000x reference)
//
#include <hip/hip_runtime.h>

typedef unsigned short u16;
typedef unsigned int u32;
typedef short bf16x8 __attribute__((ext_vector_type(8)));
typedef float f32x4 __attribute__((ext_vector_type(4)));

#define NB 128
#define NL 400
#define NT 30
#define NE 300
#define KE 320
#define NHE 512
#define NHD 512
#define NA 512
#define NV 20000
#define NVP 20096
#define K1 1024
#define N1 2048
#define NW 2048
#define OUTW (NV+NL)
#define NBLK 512

static __device__ __forceinline__ u16 f2b(float x){ u32 u=__float_as_uint(x); u += 0x7FFFu + ((u>>16)&1u); return (u16)(u>>16); }
static __device__ __forceinline__ float b2f(u16 h){ return __uint_as_float(((u32)h)<<16); }
static __device__ __forceinline__ float fsig(float x){ return 1.f/(1.f+__expf(-x)); }
static __device__ __forceinline__ float ftanh(float x){ return 1.f - 2.f/(__expf(2.f*x)+1.f); }

static __device__ __forceinline__ void gll16(const u16* g, u16* l){
  __builtin_amdgcn_global_load_lds((const __attribute__((address_space(1))) void*)g,
                                   (__attribute__((address_space(3))) void*)l, 16, 0, 0);
}

// 128x128 tile, A[M,K] x B[N,K] row-major bf16, f32 accum. 256 threads.
static __device__ __forceinline__ void gemm_core(const u16* A, int lda, const u16* Bm, int ldb,
                                                 int K, u16* lsA, u16* lsB, f32x4 (&acc)[4][4]){
  const int tid = threadIdx.x;
  const int wave = tid>>6, lane = tid&63;
  const int srow = lane>>2, sko = (lane&3)*8;
  const int wm = wave>>1, wn = wave&1;
#pragma unroll
  for (int i=0;i<4;i++)
#pragma unroll
    for (int j=0;j<4;j++)
#pragma unroll
      for (int q=0;q<4;q++) acc[i][j][q] = 0.f;
  for (int kt=0; kt<K; kt+=32){
#pragma unroll
    for (int i=0;i<2;i++){
      const int c = wave*2+i;
      const int row = c*16 + srow;
      gll16(A + (size_t)row*lda + kt + sko, lsA + c*512);
      gll16(Bm + (size_t)row*ldb + kt + sko, lsB + c*512);
    }
    __syncthreads();
    bf16x8 aF[4], bF[4];
#pragma unroll
    for (int mi=0;mi<4;mi++) aF[mi] = *(const bf16x8*)(lsA + (wm*64+mi*16+(lane&15))*32 + (lane>>4)*8);
#pragma unroll
    for (int nj=0;nj<4;nj++) bF[nj] = *(const bf16x8*)(lsB + (wn*64+nj*16+(lane&15))*32 + (lane>>4)*8);
#pragma unroll
    for (int mi=0;mi<4;mi++)
#pragma unroll
      for (int nj=0;nj<4;nj++)
        acc[mi][nj] = __builtin_amdgcn_mfma_f32_16x16x32_bf16(aF[mi], bF[nj], acc[mi][nj], 0,0,0);
    __syncthreads();
  }
}

// ---------------- setup kernels (unchanged from round 3) ----------------

__global__ __launch_bounds__(256) void k_conv_flat(const float* __restrict__ s, u16* __restrict__ d, long n){
  long i = (long)blockIdx.x*256 + threadIdx.x;
  const long st = (long)gridDim.x*256;
  for (; i<n; i+=st) d[i] = f2b(s[i]);
}

__global__ __launch_bounds__(256) void k_convpad(const float* __restrict__ s, u16* __restrict__ d,
                                                 int srows, int sk, int dk, long total){
  long i = (long)blockIdx.x*256 + threadIdx.x;
  const long st = (long)gridDim.x*256;
  for (; i<total; i+=st){
    int r = (int)(i / dk), k = (int)(i - (long)r*dk);
    d[i] = (r < srows && k < sk) ? f2b(s[(size_t)r*sk + k]) : (u16)0;
  }
}

__global__ __launch_bounds__(512) void k_transpose(const float* __restrict__ enc, u16* __restrict__ encT){
  const int b = blockIdx.y, jt = blockIdx.x;
  __shared__ float tile[16][33];
  const int tid = threadIdx.x;
  for (int lt=0; lt<25; lt++){
    {
      int l = lt*16 + (tid>>5), j = jt*32 + (tid&31);
      tile[tid>>5][tid&31] = enc[((size_t)b*NL + l)*512 + j];
    }
    __syncthreads();
    {
      int jw = tid>>4, lw = tid&15;
      encT[((size_t)b*512 + jt*32 + jw)*NL + lt*16 + lw] = f2b(tile[lw][jw]);
    }
    __syncthreads();
  }
}

__global__ __launch_bounds__(256) void k_build_w1(const float* __restrict__ Whh, const float* __restrict__ Wih, u16* __restrict__ d){
  int idx = blockIdx.x*256 + threadIdx.x;
  if (idx >= N1*K1) return;
  int n = idx >> 10, k = idx & 1023;
  float v = 0.f;
  if (n < 1024)       v = (k<512) ? Whh[(size_t)n*512 + k] : Wih[(size_t)n*812 + 300 + (k-512)];
  else if (n < 1536)  v = (k<512) ? Whh[(size_t)n*512 + k] : 0.f;
  else                v = (k<512) ? 0.f : Wih[(size_t)(n-512)*812 + 300 + (k-512)];
  d[idx] = f2b(v);
}

__global__ __launch_bounds__(256) void k_build_w2(const float* __restrict__ Wr, u16* __restrict__ d){
  int idx = blockIdx.x*256 + threadIdx.x;
  if (idx >= 512*K1) return;
  int r = idx >> 10, k = idx & 1023;
  float v = (k<512) ? Wr[(size_t)r*1324 + 812 + k] : Wr[(size_t)r*1324 + 300 + (k-512)];
  d[idx] = f2b(v);
}

__global__ __launch_bounds__(256) void k_build_wemb(const float* __restrict__ Wih, const float* __restrict__ Wr, u16* __restrict__ d){
  int idx = blockIdx.x*256 + threadIdx.x;
  if (idx >= NW*KE) return;
  int n = idx / KE, k = idx - n*KE;
  float v = 0.f;
  if (k < NE) v = (n < 1536) ? Wih[(size_t)n*812 + k] : Wr[(size_t)(n-1536)*1324 + k];
  d[idx] = f2b(v);
}

__global__ __launch_bounds__(256) void k_build_xemb(const int* __restrict__ tgt, const float* __restrict__ embed, u16* __restrict__ d){
  int idx = blockIdx.x*256 + threadIdx.x;
  if (idx >= NT*NB*KE) return;
  int row = idx / KE, k = idx - row*KE;
  int t = row >> 7, b = row & 127;
  u16 hv = 0;
  if (k < NE){
    int w = 2;
    if (t > 0){ w = tgt[b*NT + t-1]; if ((u32)w >= (u32)NV) w = 1; }
    hv = f2b(embed[(size_t)w*NE + k]);
  }
  d[idx] = hv;
}

__global__ __launch_bounds__(256) void k_init(const float* __restrict__ s_in, float* __restrict__ sbuf0, u16* __restrict__ x1){
  int idx = blockIdx.x*256 + threadIdx.x;
  if (idx < 65536){
    int b = idx>>9, j = idx&511;
    float v = s_in[idx];
    sbuf0[idx] = v;
    x1[(size_t)b*K1 + j] = f2b(v);
  } else if (idx < 131072){
    int k = idx - 65536;
    int b = k>>9, j = k&511;
    x1[(size_t)b*K1 + 512 + j] = 0;
  }
}

__global__ __launch_bounds__(256) void k_encproj(const u16* __restrict__ A, const u16* __restrict__ Bw, u16* __restrict__ C){
  __shared__ __align__(16) u16 lsA[4096], lsB[4096];
  const int n0 = blockIdx.x*128, m0 = blockIdx.y*128;
  f32x4 acc[4][4];
  gemm_core(A + (size_t)m0*512, 512, Bw + (size_t)n0*512, 512, 512, lsA, lsB, acc);
  const int tid=threadIdx.x, wave=tid>>6, lane=tid&63, wm=wave>>1, wn=wave&1;
#pragma unroll
  for (int mi=0;mi<4;mi++)
#pragma unroll
    for (int nj=0;nj<4;nj++)
#pragma unroll
      for (int q=0;q<4;q++){
        int r = m0 + wm*64 + mi*16 + (lane>>4)*4 + q;
        int c = n0 + wn*64 + nj*16 + (lane&15);
        C[(size_t)r*512 + c] = f2b(acc[mi][nj][q]);
      }
}

__global__ __launch_bounds__(256) void k_gemm_emb(const u16* __restrict__ Xe, const u16* __restrict__ We, float* __restrict__ gre){
  __shared__ __align__(16) u16 lsA[4096], lsB[4096];
  const int n0 = blockIdx.x*128, m0 = blockIdx.y*128;
  f32x4 acc[4][4];
  gemm_core(Xe + (size_t)m0*KE, KE, We + (size_t)n0*KE, KE, KE, lsA, lsB, acc);
  const int tid=threadIdx.x, wave=tid>>6, lane=tid&63, wm=wave>>1, wn=wave&1;
#pragma unroll
  for (int mi=0;mi<4;mi++)
#pragma unroll
    for (int nj=0;nj<4;nj++)
#pragma unroll
      for (int q=0;q<4;q++){
        int r = m0 + wm*64 + mi*16 + (lane>>4)*4 + q;
        int c = n0 + wn*64 + nj*16 + (lane&15);
        gre[(size_t)r*NW + c] = acc[mi][nj][q];
      }
}

__global__ __launch_bounds__(256) void k_gemm1(const u16* __restrict__ x1, const u16* __restrict__ W1, float* __restrict__ g){
  __shared__ __align__(16) u16 lsA[4096], lsB[4096];
  const int n0 = blockIdx.x*128;
  f32x4 acc[4][4];
  gemm_core(x1, K1, W1 + (size_t)n0*K1, K1, K1, lsA, lsB, acc);
  const int tid=threadIdx.x, wave=tid>>6, lane=tid&63, wm=wave>>1, wn=wave&1;
#pragma unroll
  for (int mi=0;mi<4;mi++)
#pragma unroll
    for (int nj=0;nj<4;nj++)
#pragma unroll
      for (int q=0;q<4;q++){
        int r = wm*64 + mi*16 + (lane>>4)*4 + q;
        int c = n0 + wn*64 + nj*16 + (lane&15);
        g[(size_t)r*N1 + c] = acc[mi][nj][q];
      }
}

// ---------------- persistent step-loop kernel ----------------

struct KP {
  const float *bih, *bhh, *attb, *attv, *copyW, *copyb, *readb;
  const int   *src;
  const u16   *Wsb, *eproj, *encT, *W1, *W2, *WoP;
  const float *gre;
  float *g, *sbufA, *sbufB, *e_part, *attn_ws, *ctx_ws, *pcb, *parts, *energy, *out;
  u16   *x1, *mbf;
  u32   *bar;
};

static __device__ __forceinline__ void gbar(u32* cnt, u32* gen){
  __syncthreads();
  if (threadIdx.x==0){
    __threadfence();
    u32 g0 = __hip_atomic_load(gen, __ATOMIC_RELAXED, __HIP_MEMORY_SCOPE_AGENT);
    u32 my = __hip_atomic_fetch_add(cnt, 1u, __ATOMIC_ACQ_REL, __HIP_MEMORY_SCOPE_AGENT);
    if (my == (u32)(NBLK-1)){
      __hip_atomic_store(cnt, 0u, __ATOMIC_RELAXED, __HIP_MEMORY_SCOPE_AGENT);
      __hip_atomic_fetch_add(gen, 1u, __ATOMIC_ACQ_REL, __HIP_MEMORY_SCOPE_AGENT);
    } else {
      while (__hip_atomic_load(gen, __ATOMIC_RELAXED, __HIP_MEMORY_SCOPE_AGENT) == g0)
        __builtin_amdgcn_s_sleep(4);
      (void)__hip_atomic_load(gen, __ATOMIC_ACQUIRE, __HIP_MEMORY_SCOPE_AGENT);
    }
  }
  __syncthreads();
}

// gru + q-proj + e-score partials for step tq. u in 0..255: b=u>>1, y=a-half
static __device__ void ph_gqe(const KP& p, char* sm, int u, int tq){
  const int tid = threadIdx.x;
  const int b = u>>1, y = u&1;
  float* s_lds = (float*)sm;          // 512 f
  float* q_lds = (float*)(sm+2048);   // 256 f
  const float* gb = p.g + (size_t)b*N1;
  const float* ge = p.gre + ((size_t)(tq*NB + b))*NW;
  const float* s_old = (tq&1) ? p.sbufB : p.sbufA;
  float* s_new       = (tq&1) ? p.sbufA : p.sbufB;
#pragma unroll
  for (int h=0; h<2; h++){
    const int j = tid + h*256;
    float r = fsig(gb[j] + ge[j] + p.bih[j] + p.bhh[j]);
    float z = fsig(gb[512+j] + ge[512+j] + p.bih[512+j] + p.bhh[512+j]);
    float n = ftanh(ge[1024+j] + gb[1536+j] + p.bih[1024+j] + r*(gb[1024+j] + p.bhh[1024+j]));
    float sn = (1.f-z)*n + z*s_old[(size_t)b*512 + j];
    s_lds[j] = sn;
    if (y==0){ s_new[(size_t)b*512 + j] = sn; p.x1[(size_t)b*K1 + j] = f2b(sn); }
  }
  __syncthreads();
  {
    const int a = y*256 + tid;
    const u16* wr = p.Wsb + (size_t)a*512;
    float acc = 0.f;
#pragma unroll 4
    for (int k=0;k<512;k+=8){
      bf16x8 w = *(const bf16x8*)(wr + k);
#pragma unroll
      for (int j=0;j<8;j++) acc += s_lds[k+j]*b2f((u16)w[j]);
    }
    q_lds[tid] = acc + p.attb[a];
  }
  __syncthreads();
  const int lane = tid&63, wv = tid>>6;
  float v4[4], q4[4];
#pragma unroll
  for (int j=0;j<4;j++){ v4[j]=p.attv[y*256 + lane*4 + j]; q4[j]=q_lds[lane*4 + j]; }
  float* epo = p.e_part + ((size_t)y*NB + b)*NL;
#pragma unroll 2
  for (int i=0;i<100;i++){
    const int l = 4*i + wv;
    const u16* ep = p.eproj + ((size_t)b*NL + l)*512 + y*256 + lane*4;
    const uint2 pk = *(const uint2*)ep;
    float acc = v4[0]*ftanh(b2f((u16)(pk.x&0xFFFFu)) + q4[0]);
    acc += v4[1]*ftanh(b2f((u16)(pk.x>>16)) + q4[1]);
    acc += v4[2]*ftanh(b2f((u16)(pk.y&0xFFFFu)) + q4[2]);
    acc += v4[3]*ftanh(b2f((u16)(pk.y>>16)) + q4[3]);
    for (int off=32; off; off>>=1) acc += __shfl_xor(acc, off);
    if (lane==0) epo[l] = acc;
  }
}

// softmax + ctx for step tq. u in 0..255: b=u>>1, y=j-half
static __device__ void ph_smctx(const KP& p, char* sm, int u, int tq){
  const int tid = threadIdx.x;
  const int b = u>>1, y = u&1;
  const int lane = tid&63, wv = tid>>6;
  float* a_lds = (float*)sm;            // 400 f
  float* red   = (float*)(sm+1664);     // 4 f
  float* bc    = (float*)(sm+1696);     // 2 f
  float e0 = p.e_part[(size_t)b*NL + tid] + p.e_part[((size_t)NB + b)*NL + tid];
  float ev0 = (p.src[b*NL + tid]==0) ? -INFINITY : e0;
  float ev1 = -INFINITY;
  if (tid < NL-256){
    float e1 = p.e_part[(size_t)b*NL + tid+256] + p.e_part[((size_t)NB + b)*NL + tid+256];
    ev1 = (p.src[b*NL + tid+256]==0) ? -INFINITY : e1;
  }
  float mx = fmaxf(ev0, ev1);
  for (int off=32; off; off>>=1) mx = fmaxf(mx, __shfl_xor(mx, off));
  if (lane==0) red[wv]=mx;
  __syncthreads();
  if (tid==0) bc[0] = fmaxf(fmaxf(red[0],red[1]), fmaxf(red[2],red[3]));
  __syncthreads();
  const float M = bc[0];
  float p0 = (ev0==-INFINITY)? 0.f : __expf(ev0 - M);
  float p1 = (ev1==-INFINITY)? 0.f : __expf(ev1 - M);
  float sm2 = p0 + p1;
  for (int off=32; off; off>>=1) sm2 += __shfl_xor(sm2, off);
  if (lane==0) red[wv]=sm2;
  __syncthreads();
  if (tid==0) bc[1] = red[0]+red[1]+red[2]+red[3];
  __syncthreads();
  const float inv = 1.f / bc[1];
  a_lds[tid] = p0*inv;
  if (tid < NL-256) a_lds[tid+256] = p1*inv;
  __syncthreads();
  if (y==0){
    float* ab = p.attn_ws + ((size_t)(tq&1)*NB + b)*NL;
    ab[tid] = a_lds[tid];
    if (tid < NL-256) ab[tid+256] = a_lds[tid+256];
  }
  // ctx
  const int j = y*256 + tid;
  const u16* er = p.encT + ((size_t)b*512 + j)*NL;
  float c0=0.f, c1=0.f;
#pragma unroll 5
  for (int m=0;m<NL;m+=16){
    bf16x8 e8 = *(const bf16x8*)(er + m);
    bf16x8 f8 = *(const bf16x8*)(er + m + 8);
#pragma unroll
    for (int jj=0;jj<8;jj++){ c0 += a_lds[m+jj]*b2f((u16)e8[jj]); c1 += a_lds[m+8+jj]*b2f((u16)f8[jj]); }
  }
  const float ctx = c0+c1;
  p.x1[(size_t)b*K1 + 512 + j] = f2b(ctx);
  p.ctx_ws[(size_t)b*512 + j] = ctx;
}

static __device__ void ph_gemm1(const KP& p, char* sm, int u){
  u16* lsA = (u16*)sm; u16* lsB = (u16*)(sm+8192);
  const int n0 = u*128;
  f32x4 acc[4][4];
  gemm_core(p.x1, K1, p.W1 + (size_t)n0*K1, K1, K1, lsA, lsB, acc);
  const int tid=threadIdx.x, wave=tid>>6, lane=tid&63, wm=wave>>1, wn=wave&1;
#pragma unroll
  for (int mi=0;mi<4;mi++)
#pragma unroll
    for (int nj=0;nj<4;nj++)
#pragma unroll
      for (int q=0;q<4;q++){
        int r = wm*64 + mi*16 + (lane>>4)*4 + q;
        int c = n0 + wn*64 + nj*16 + (lane&15);
        p.g[(size_t)r*N1 + c] = acc[mi][nj][q];
      }
}

static __device__ void ph_read(const KP& p, char* sm, int u, int t){
  u16* lsA = (u16*)sm; u16* lsB = (u16*)(sm+8192);
  const int n0 = u*128;
  f32x4 acc[4][4];
  gemm_core(p.x1, K1, p.W2 + (size_t)n0*K1, K1, K1, lsA, lsB, acc);
  const int tid=threadIdx.x, wave=tid>>6, lane=tid&63, wm=wave>>1, wn=wave&1;
#pragma unroll
  for (int mi=0;mi<4;mi++)
#pragma unroll
    for (int nj=0;nj<4;nj++)
#pragma unroll
      for (int q=0;q<4;q++){
        int r = wm*64 + mi*16 + (lane>>4)*4 + q;
        int c = n0 + wn*64 + nj*16 + (lane&15);
        float v = acc[mi][nj][q] + p.readb[c] + p.gre[((size_t)(t*NB + r))*NW + 1536 + c];
        float o = __shfl_xor(v, 1);
        float mx2 = fmaxf(v, o);
        if (!(lane&1)) p.mbf[(size_t)r*256 + (c>>1)] = f2b(mx2);
      }
}

static __device__ void ph_pcopy(const KP& p, int u, int t){
  const int tid = threadIdx.x;
  const float* sN = (t&1) ? p.sbufA : p.sbufB;   // output of step t
  const int b = u*32 + (tid>>3), kq = tid&7;
  const float* v = (kq<4) ? (sN + (size_t)b*512 + kq*128) : (p.ctx_ws + (size_t)b*512 + (kq-4)*128);
  const float* w = p.copyW + kq*128;
  float acc = 0.f;
#pragma unroll 8
  for (int k=0;k<128;k+=4){
    const float4 vv = *(const float4*)(v+k);
    const float4 ww = *(const float4*)(w+k);
    acc += vv.x*ww.x + vv.y*ww.y + vv.z*ww.z + vv.w*ww.w;
  }
  acc += __shfl_xor(acc,1); acc += __shfl_xor(acc,2); acc += __shfl_xor(acc,4);
  if (kq==0) p.pcb[b] = fsig(acc + p.copyb[0]);
}

static __device__ void ph_energy(const KP& p, char* sm, int u){
  u16* lsA = (u16*)sm; u16* lsB = (u16*)(sm+8192);
  float (*psum)[2] = (float(*)[2])(sm+16384);
  const int n0 = u*128;
  f32x4 acc[4][4];
  gemm_core(p.mbf, 256, p.WoP + (size_t)n0*256, 256, 256, lsA, lsB, acc);
  const int tid=threadIdx.x, wave=tid>>6, lane=tid&63, wm=wave>>1, wn=wave&1;
  float rs[4][4];
#pragma unroll
  for (int mi=0;mi<4;mi++)
#pragma unroll
    for (int q=0;q<4;q++) rs[mi][q]=0.f;
#pragma unroll
  for (int mi=0;mi<4;mi++)
#pragma unroll
    for (int nj=0;nj<4;nj++){
      const int c = n0 + wn*64 + nj*16 + (lane&15);
#pragma unroll
      for (int q=0;q<4;q++){
        const int r = wm*64 + mi*16 + (lane>>4)*4 + q;
        float e = acc[mi][nj][q];
        if (c < NV){ p.energy[(size_t)r*NV + c] = e; rs[mi][q] += __expf(e); }
      }
    }
#pragma unroll
  for (int mi=0;mi<4;mi++)
#pragma unroll
    for (int q=0;q<4;q++){
      float v = rs[mi][q];
      v += __shfl_xor(v,1); v += __shfl_xor(v,2); v += __shfl_xor(v,4); v += __shfl_xor(v,8);
      if ((lane&15)==0) psum[wm*64 + mi*16 + (lane>>4)*4 + q][wn] = v;
    }
  __syncthreads();
  if (tid < 128) p.parts[(size_t)tid*160 + u] = psum[tid][0] + psum[tid][1];
}

static __device__ void ph_out(const KP& p, char* sm, int u, int t){
  const int tid = threadIdx.x;
  const int b = u>>1, half = u&1;
  const int lane = tid&63, wv = tid>>6;
  float* red = (float*)sm;
  float* bc  = (float*)(sm+64);
  float v = (tid<157)? p.parts[(size_t)b*160 + tid] : 0.f;
  for (int off=32; off; off>>=1) v += __shfl_xor(v, off);
  if (lane==0) red[wv]=v;
  __syncthreads();
  if (tid==0){ bc[0] = __logf(red[0]+red[1]+red[2]+red[3]); float pc = p.pcb[b]; bc[1] = 1.f - pc; bc[2] = pc; }
  __syncthreads();
  const float LSE = bc[0], omp = bc[1], pcv = bc[2];
  float* orow = p.out + ((size_t)b*NT + t)*OUTW;
  const float* eb = p.energy + (size_t)b*NV + half*10000;
  float* ob = orow + half*10000;
  for (int i=tid; i<10000; i+=256) ob[i] = __logf(omp*__expf(eb[i]-LSE) + 1e-12f);
  if (half==0){
    const float* aw = p.attn_ws + ((size_t)(t&1)*NB + b)*NL;
    for (int i=tid; i<NL; i+=256) orow[NV + i] = __logf(pcv*aw[i] + 1e-12f);
  }
}

__global__ __launch_bounds__(256,2) void k_persist(KP p){
  __shared__ __align__(16) char sm[17664];
  const int blk = blockIdx.x;
  u32* cnt = p.bar;
  u32* gen = p.bar + 32;
  for (int t=-1; t<NT; ++t){
    if (t>=0){
      if (blk < 16)       ph_gemm1(p, sm, blk);
      else if (blk < 20)  ph_read(p, sm, blk-16, t);
      else if (blk < 24)  ph_pcopy(p, blk-20, t);
    }
    gbar(cnt, gen);
    if (t>=0 && blk < 157) ph_energy(p, sm, blk);
    if (t+1<NT && blk >= 157 && blk < 413) ph_gqe(p, sm, blk-157, t+1);
    gbar(cnt, gen);
    if (t>=0 && blk < 256) ph_out(p, sm, blk, t);
    if (t+1<NT && blk >= 256) ph_smctx(p, sm, blk-256, t+1);
    if (t+1<NT) gbar(cnt, gen);
  }
}

// ---------------- launch ----------------

extern "C" void kernel_launch(void* const* d_in, const int* in_sizes, int n_in,
                              void* d_out, int out_size, void* d_ws, size_t ws_size,
                              hipStream_t stream){
  const float* enc   = (const float*)d_in[0];
  const float* s_in  = (const float*)d_in[1];
  const int*   src   = (const int*)d_in[2];
  const int*   tgt   = (const int*)d_in[3];
  const float* embed = (const float*)d_in[4];
  const float* W_ih  = (const float*)d_in[5];
  const float* b_ih  = (const float*)d_in[6];
  const float* W_hh  = (const float*)d_in[7];
  const float* b_hh  = (const float*)d_in[8];
  const float* attWh = (const float*)d_in[9];
  const float* attWs = (const float*)d_in[10];
  const float* attb  = (const float*)d_in[11];
  const float* attv  = (const float*)d_in[12];
  const float* copyW = (const float*)d_in[13];
  const float* copyb = (const float*)d_in[14];
  const float* readW = (const float*)d_in[15];
  const float* readb = (const float*)d_in[16];
  const float* readWo= (const float*)d_in[17];
  float* out = (float*)d_out;
  (void)in_sizes; (void)n_in; (void)out_size; (void)ws_size;

  char* wsp = (char*)d_ws;
  size_t off = 0;
  auto alloc = [&](size_t bytes)->char*{ char* p = wsp + off; off = (off + bytes + 255) & ~(size_t)255; return p; };
  u16* enc_bf   = (u16*)alloc((size_t)NB*NL*NHE*2);
  u16* encT     = (u16*)alloc((size_t)NB*NHE*NL*2);
  u16* eproj    = (u16*)alloc((size_t)NB*NL*NA*2);
  u16* attWh_bf = (u16*)alloc((size_t)NA*NHE*2);
  u16* Wsb      = (u16*)alloc((size_t)NA*NHD*2);
  u16* W1       = (u16*)alloc((size_t)N1*K1*2);
  u16* W2       = (u16*)alloc((size_t)512*K1*2);
  u16* Wemb     = (u16*)alloc((size_t)NW*KE*2);
  u16* Xemb     = (u16*)alloc((size_t)NT*NB*KE*2);
  u16* WoP      = (u16*)alloc((size_t)NVP*256*2);
  float* gre    = (float*)alloc((size_t)NT*NB*NW*4);
  float* g      = (float*)alloc((size_t)NB*N1*4);
  u16* x1       = (u16*)alloc((size_t)NB*K1*2);
  float* sbufA  = (float*)alloc((size_t)NB*NHD*4);
  float* sbufB  = (float*)alloc((size_t)NB*NHD*4);
  float* e_part = (float*)alloc((size_t)2*NB*NL*4);
  float* attn_ws= (float*)alloc((size_t)2*NB*NL*4);
  float* ctx_ws = (float*)alloc((size_t)NB*NHE*4);
  u16* mbf      = (u16*)alloc((size_t)NB*256*2);
  float* energy = (float*)alloc((size_t)NB*NV*4);
  float* parts  = (float*)alloc((size_t)NB*160*4);
  float* pcb    = (float*)alloc((size_t)NB*4);
  u32* bar      = (u32*)alloc(512);

  hipMemsetAsync(bar, 0, 512, stream);

  k_conv_flat<<<4096,256,0,stream>>>(enc, enc_bf, (long)NB*NL*NHE);
  k_transpose<<<dim3(16,128),512,0,stream>>>(enc, encT);
  k_conv_flat<<<1024,256,0,stream>>>(attWh, attWh_bf, (long)NA*NHE);
  k_conv_flat<<<1024,256,0,stream>>>(attWs, Wsb, (long)NA*NHD);
  k_build_w1<<<8192,256,0,stream>>>(W_hh, W_ih, W1);
  k_build_w2<<<2048,256,0,stream>>>(readW, W2);
  k_build_wemb<<<2560,256,0,stream>>>(W_ih, readW, Wemb);
  k_build_xemb<<<4800,256,0,stream>>>(tgt, embed, Xemb);
  k_convpad<<<2048,256,0,stream>>>(readWo, WoP, NV, 256, 256, (long)NVP*256);
  k_init<<<512,256,0,stream>>>(s_in, sbufA, x1);
  k_encproj<<<dim3(4,400),256,0,stream>>>(enc_bf, attWh_bf, eproj);
  k_gemm_emb<<<dim3(16,30),256,0,stream>>>(Xemb, Wemb, gre);
  k_gemm1<<<16,256,0,stream>>>(x1, W1, g);

  KP kp;
  kp.bih = b_ih; kp.bhh = b_hh; kp.attb = attb; kp.attv = attv;
  kp.copyW = copyW; kp.copyb = copyb; kp.readb = readb;
  kp.src = src;
  kp.Wsb = Wsb; kp.eproj = eproj; kp.encT = encT; kp.W1 = W1; kp.W2 = W2; kp.WoP = WoP;
  kp.gre = gre;
  kp.g = g; kp.sbufA = sbufA; kp.sbufB = sbufB; kp.e_part = e_part;
  kp.attn_ws = attn_ws; kp.ctx_ws = ctx_ws; kp.pcb = pcb; kp.parts = parts;
  kp.energy = energy; kp.out = out;
  kp.x1 = x1; kp.mbf = mbf;
  kp.bar = bar;

  k_persist<<<NBLK,256,0,stream>>>(kp);
}